// Round 5
// baseline (903.175 us; speedup 1.0000x reference)
//
#include <hip/hip_runtime.h>
#include <hip/hip_bf16.h>

#define NEG 0.01f

using f32x4  = __attribute__((ext_vector_type(4))) float;
using bf16x8 = __attribute__((ext_vector_type(8))) short;

__device__ __forceinline__ unsigned short f2b(float f) {
  union { float f; unsigned int u; } v; v.f = f;
  unsigned int r = (v.u + 0x7fffu + ((v.u >> 16) & 1u)) >> 16;
  return (unsigned short)r;
}
__device__ __forceinline__ float b2f(unsigned int bits) {
  union { unsigned int u; float f; } v; v.u = bits << 16;
  return v.f;
}

__device__ __forceinline__ void gload16(const unsigned short* g, unsigned short* l) {
  __builtin_amdgcn_global_load_lds(
      (const __attribute__((address_space(1))) unsigned int*)g,
      (__attribute__((address_space(3))) unsigned int*)l, 16, 0, 0);
}

// ---- fp32 -> bf16 bulk convert ----
__global__ void k_cvt(const float* __restrict__ in, unsigned short* __restrict__ out, int n4) {
  int i = blockIdx.x * blockDim.x + threadIdx.x;
  int stride = gridDim.x * blockDim.x;
  for (; i < n4; i += stride) {
    float4 v = reinterpret_cast<const float4*>(in)[i];
    ushort4 o;
    o.x = f2b(v.x); o.y = f2b(v.y); o.z = f2b(v.z); o.w = f2b(v.w);
    reinterpret_cast<ushort4*>(out)[i] = o;
  }
}

// ---- triangular-masked weight convert (anti=1 folds the layer-2 flip) ----
__global__ void k_cvt_tri(const float* __restrict__ W, unsigned short* __restrict__ out, int anti) {
  const int H = 2048;
  int i = blockIdx.x;
  const float* wr = W + (size_t)i * H;
  unsigned short* orow = out + (size_t)i * H;
  if (!anti) {
    for (int j = threadIdx.x; j < H; j += blockDim.x) {
      float v = (j >= i) ? wr[j] : 0.f;
      orow[j] = f2b(v);
    }
  } else {
    for (int k = threadIdx.x; k < H; k += blockDim.x) {
      int j = H - 1 - k;
      float v = (j >= i) ? wr[j] : 0.f;
      orow[k] = f2b(v);
    }
  }
}

// ---- 8-phase-style bf16 MFMA GEMM, C = lrelu(A @ B^T + bias) stored bf16.
// Tile 256x256, BK=64, 512 threads = 8 waves (2 row-halves x 4 col-quarters),
// wave tile 128x64 (acc 8x4 of 16x16).  LDS: 2 bufs x (A 32KB + B 32KB) =
// 128KB.  Per K-tile: 4 quadrant phases {12 ds_read_b128 -> barrier -> 16
// MFMA (setprio) -> barrier}; stage tile t+2 after end-of-iter fence;
// counted vmcnt(8) at iter top (never 0 mid-loop).
// LDS layout: 1KB subtiles (16 rows x 32 bf16); within subtile chunk (r,g)
// at byte r*64 + ((g + (r>>1))&3)*16  -> quarter-wave reads hit each bank
// quad exactly twice (free).  Write side: gload_lds is linear, so the
// per-lane GLOBAL source k-slot is pre-rotated by the same amount (rule 21).
// mode: 0=full K, 1=upper-tri (kstart=bcol), 2=anti (kend=K-bcol) ----
__launch_bounds__(512, 2)
__global__ void k_gemm8(const unsigned short* __restrict__ A, int lda,
                        const unsigned short* __restrict__ B, int ldb,
                        const float* __restrict__ bias,
                        unsigned short* __restrict__ C, int ldc,
                        int K, int mode) {
  extern __shared__ unsigned short lds[];
  const int tid = threadIdx.x;
  const int w   = tid >> 6;
  const int l   = tid & 63;

  // XCD-chunked swizzle + diagonal col scramble (nwg % 8 == 0)
  const int nwg = gridDim.x;
  const int q8  = nwg >> 3;
  const int L   = blockIdx.x;
  const int logical = (L & 7) * q8 + (L >> 3);
  const int by = logical >> 3;
  const int bx = (logical + by) & 7;
  const int brow = by * 256;
  const int bcol = bx * 256;

  int kstart = 0, kend = K;
  if (mode == 1) kstart = bcol;
  else if (mode == 2) kend = K - bcol;
  const int nt = (kend - kstart) >> 6;   // K-tiles of 64, >= 1

  const int wm = w >> 2;   // 0..1 row half
  const int wn = w & 3;    // 0..3 col quarter

  f32x4 acc[8][4];
#pragma unroll
  for (int i = 0; i < 8; i++)
#pragma unroll
    for (int j = 0; j < 4; j++) acc[i][j] = (f32x4){0.f, 0.f, 0.f, 0.f};

  // staging constants: lane l writes LDS byte l*16 of its subtile ->
  // phys (row=l>>2, slot=l&3) -> logical k-slot g = (slot - (row>>1)) & 3
  const int srow  = l >> 2;
  const int sperm = ((l & 3) - ((l >> 3) & 3)) & 3;
  const unsigned short* Asrc = A + (size_t)(brow + w * 16 + srow) * lda + sperm * 8;
  const unsigned short* Bsrc = B + (size_t)(bcol + w * 16 + srow) * ldb + sperm * 8;
  // read: lane l wants (r=l&15, g=l>>4) -> byte r*64 + ((g + (r>>1))&3)*16
  const int rdoff = (l & 15) * 64 + ((((l >> 4) + ((l >> 1) & 7)) & 3) << 4);

  auto ldsAt = [&](int byteoff) -> unsigned short* {
    return (unsigned short*)((char*)lds + byteoff);
  };
  auto stage_tile = [&](int tk, int bb) {
    const int kc = kstart + (tk << 6);
#pragma unroll
    for (int half = 0; half < 2; half++) {
#pragma unroll
      for (int qq = 0; qq < 2; qq++) {
        gload16(Asrc + (size_t)(half * 128) * lda + kc + qq * 32,
                ldsAt(bb * 65536 + half * 16384 + (w * 2 + qq) * 1024));
        gload16(Bsrc + (size_t)(half * 128) * ldb + kc + qq * 32,
                ldsAt(bb * 65536 + 32768 + half * 16384 + (w * 2 + qq) * 1024));
      }
    }
  };

  // prologue: stage tiles 0 and 1
  stage_tile(0, 0);
  if (nt > 1) stage_tile(1, 1);

  const int AbaseW = wm * 16384;
  const int BbaseW = 32768 + (wn >> 1) * 16384 + (wn & 1) * 8192;

  for (int t = 0; t < nt; t++) {
    const int bb = t & 1;
    const int Ab = bb * 65536 + AbaseW;
    const int Bb = bb * 65536 + BbaseW;
    // gate: tile t's 8 per-thread loads have landed (counted, not 0)
    if (t + 1 < nt) asm volatile("s_waitcnt vmcnt(8)" ::: "memory");
    else            asm volatile("s_waitcnt vmcnt(0)" ::: "memory");
    __builtin_amdgcn_s_barrier();
    asm volatile("" ::: "memory");   // keep reads below the barrier

    bf16x8 aR[4][2], bR[2][2];
#pragma unroll
    for (int Q = 0; Q < 4; Q++) {
      const int mh = Q >> 1, nh = Q & 1;
      if (nh == 0) {
#pragma unroll
        for (int ii = 0; ii < 4; ii++)
#pragma unroll
          for (int kk = 0; kk < 2; kk++)
            aR[ii][kk] = *(const bf16x8*)((char*)lds + Ab + ((mh * 4 + ii) * 2 + kk) * 1024 + rdoff);
      }
#pragma unroll
      for (int jj = 0; jj < 2; jj++)
#pragma unroll
        for (int kk = 0; kk < 2; kk++)
          bR[jj][kk] = *(const bf16x8*)((char*)lds + Bb + ((nh * 2 + jj) * 2 + kk) * 1024 + rdoff);

      __builtin_amdgcn_s_setprio(1);
#pragma unroll
      for (int ii = 0; ii < 4; ii++)
#pragma unroll
        for (int jj = 0; jj < 2; jj++) {
          acc[mh * 4 + ii][nh * 2 + jj] = __builtin_amdgcn_mfma_f32_16x16x32_bf16(
              aR[ii][0], bR[jj][0], acc[mh * 4 + ii][nh * 2 + jj], 0, 0, 0);
          acc[mh * 4 + ii][nh * 2 + jj] = __builtin_amdgcn_mfma_f32_16x16x32_bf16(
              aR[ii][1], bR[jj][1], acc[mh * 4 + ii][nh * 2 + jj], 0, 0, 0);
        }
      __builtin_amdgcn_s_setprio(0);
      if (Q < 3) __builtin_amdgcn_s_barrier();
    }
    // end-of-iteration fence: every wave's reads of buf bb are complete
    // before any wave's restage data can land (gload latency >> 0).
    asm volatile("s_waitcnt lgkmcnt(0)" ::: "memory");
    __builtin_amdgcn_s_barrier();
    asm volatile("" ::: "memory");
    if (t + 2 < nt) stage_tile(t + 2, bb);
  }

  // epilogue: bias + leaky-relu + bf16 store
  const int orow0 = brow + wm * 128 + ((l >> 4) << 2);
  const int ocol0 = bcol + wn * 64 + (l & 15);
#pragma unroll
  for (int j = 0; j < 4; j++) {
    const int col = ocol0 + j * 16;
    const float bv = bias[col];
#pragma unroll
    for (int i = 0; i < 8; i++) {
#pragma unroll
      for (int r = 0; r < 4; r++) {
        const int row = orow0 + i * 16 + r;
        float v = acc[i][j][r] + bv;
        v = v > 0.f ? v : NEG * v;
        C[(size_t)row * ldc + col] = f2b(v);
      }
    }
  }
}

// ---- final layer: out[n,0..2] = A[n,:] @ ow^T + ob ----
__global__ void k_out(const unsigned short* __restrict__ A,
                      const float* __restrict__ ow, const float* __restrict__ ob,
                      float* __restrict__ out) {
  const int H = 2048;
  int w = threadIdx.x >> 6, lane = threadIdx.x & 63;
  size_t n = (size_t)blockIdx.x * 4 + w;
  const unsigned short* a = A + n * H;
  float s0 = 0.f, s1 = 0.f, s2 = 0.f;
  for (int h0 = lane * 8; h0 < H; h0 += 512) {
    uint4 u = *reinterpret_cast<const uint4*>(&a[h0]);
    unsigned int uu[4] = {u.x, u.y, u.z, u.w};
#pragma unroll
    for (int q = 0; q < 4; q++) {
      int h = h0 + q * 2;
      float x0 = b2f(uu[q] & 0xffffu);
      float x1 = b2f(uu[q] >> 16);
      s0 += x0 * ow[h]         + x1 * ow[h + 1];
      s1 += x0 * ow[H + h]     + x1 * ow[H + h + 1];
      s2 += x0 * ow[2 * H + h] + x1 * ow[2 * H + h + 1];
    }
  }
#pragma unroll
  for (int off = 32; off > 0; off >>= 1) {
    s0 += __shfl_down(s0, off);
    s1 += __shfl_down(s1, off);
    s2 += __shfl_down(s2, off);
  }
  if (lane == 0) {
    out[n * 3 + 0] = s0 + ob[0];
    out[n * 3 + 1] = s1 + ob[1];
    out[n * 3 + 2] = s2 + ob[2];
  }
}

extern "C" void kernel_launch(void* const* d_in, const int* in_sizes, int n_in,
                              void* d_out, int out_size, void* d_ws, size_t ws_size,
                              hipStream_t stream) {
  const int N = 32768, H = 2048, INF_ = 64;
  const float* p      = (const float*)d_in[0];
  const float* init_w = (const float*)d_in[1];
  const float* init_b = (const float*)d_in[2];
  const float* w1     = (const float*)d_in[3];
  const float* b1     = (const float*)d_in[4];
  const float* w2     = (const float*)d_in[5];
  const float* b2     = (const float*)d_in[6];
  const float* w3     = (const float*)d_in[7];
  const float* b3     = (const float*)d_in[8];
  const float* ow     = (const float*)d_in[9];
  const float* ob     = (const float*)d_in[10];

  // allow 128KB dynamic LDS for the GEMM (host-side, idempotent)
  hipFuncSetAttribute((const void*)k_gemm8,
                      hipFuncAttributeMaxDynamicSharedMemorySize, 131072);

  char* wsb = (char*)d_ws;
  size_t off = 0;
  auto alloc = [&](size_t bytes) -> char* {
    char* q = wsb + off;
    off += (bytes + 255) & ~(size_t)255;
    return q;
  };
  unsigned short* pb  = (unsigned short*)alloc((size_t)N * INF_ * 2);
  unsigned short* iwb = (unsigned short*)alloc((size_t)H * INF_ * 2);
  unsigned short* w1m = (unsigned short*)alloc((size_t)H * H * 2);
  unsigned short* w2m = (unsigned short*)alloc((size_t)H * H * 2);
  unsigned short* w3m = (unsigned short*)alloc((size_t)H * H * 2);

  size_t remain = (ws_size > off) ? (ws_size - off) : 0;
  long long ncll = (long long)(remain / ((size_t)H * 2 * 2));
  int Nc = (int)((ncll / 256) * 256);     // multiple of 256 for the 256-tile
  if (Nc > N) Nc = N;
  if (Nc < 256) return;  // ws too small: leave d_out poisoned (clean failure)

  unsigned short* bufA = (unsigned short*)(wsb + off);
  unsigned short* bufB = bufA + (size_t)Nc * H;

  k_cvt<<<2048, 256, 0, stream>>>(p, pb, N * INF_ / 4);
  k_cvt<<<32,   256, 0, stream>>>(init_w, iwb, H * INF_ / 4);
  k_cvt_tri<<<H, 256, 0, stream>>>(w1, w1m, 0);
  k_cvt_tri<<<H, 256, 0, stream>>>(w2, w2m, 0);
  k_cvt_tri<<<H, 256, 0, stream>>>(w3, w3m, 1);

  for (int n0 = 0; n0 < N; n0 += Nc) {
    int nc = (N - n0 < Nc) ? (N - n0) : Nc;
    int nblk = (nc / 256) * (H / 256);   // 1D grid, multiple of 8
    // layer 0: K=64 (single K-tile)
    k_gemm8<<<nblk, 512, 131072, stream>>>(pb + (size_t)n0 * INF_, INF_, iwb, INF_,
                                           init_b, bufA, H, INF_, 0);
    // layer 1 (upper-tri)
    k_gemm8<<<nblk, 512, 131072, stream>>>(bufA, H, w1m, H, b1, bufB, H, H, 1);
    // layer 2 (upper-tri; flip folded into w3m)
    k_gemm8<<<nblk, 512, 131072, stream>>>(bufB, H, w2m, H, b2, bufA, H, H, 1);
    // layer 3 (anti-tri, pre-flipped weights)
    k_gemm8<<<nblk, 512, 131072, stream>>>(bufA, H, w3m, H, b3, bufB, H, H, 2);
    // out head
    k_out<<<nc / 4, 256, 0, stream>>>(bufB, ow, ob, (float*)d_out + (size_t)n0 * 3);
  }
}